// Round 1
// baseline (1050.908 us; speedup 1.0000x reference)
//
#include <hip/hip_runtime.h>
#include <hip/hip_bf16.h>
#include <math.h>

// Problem constants: B=4, C=256, H=W=64 -> N=4096, QP=32.
// Decomposition:
//   qT[b,n,p] = sum_c Wq[p,c] x[b,c,n] + bq[p]          (q_i contiguous)
//   kT[b,j,p] = sum_c Wk[p,c] x[b,c,j] + bk[p]          (k_j contiguous)
//   vT[b,n,o] = sum_c Wv[o,c] x[b,c,n] + bv[o]          (v^T: row n over o)
//   out[b,c,j] = gamma * (sum_i softmax_i(qT[i]·kT[j]) * vT[i,c]) + x[b,c,j]
// Flash-style over i (the softmax axis), never materializing N x N.

#define NBATCH 4
#define CDIM   256
#define NSEQ   4096
#define QPDIM  32

// ---------------------------------------------------------------------------
// Kernel 1: QKV projections.  grid = B * (N/64) = 256 blocks, 512 threads.
// Each block: one batch b, one 64-column tile of n.  x-tile staged in LDS.
// Thread mapping: n = t & 63 (lane), og = t >> 6 (wave id, 0..7, wave-uniform).
//   V: og handles output rows o = og*32 .. og*32+31 (8 waves x 32 = 256 rows)
//   QK: combined 64 rows (q0..31,k0..31): og handles rows og*8 .. og*8+7
// Weight indices are wave-uniform -> scalar loads.
// ---------------------------------------------------------------------------
__global__ __launch_bounds__(512) void qkv_kernel(
    const float* __restrict__ x,
    const float* __restrict__ Wq, const float* __restrict__ bq,
    const float* __restrict__ Wk, const float* __restrict__ bk,
    const float* __restrict__ Wv, const float* __restrict__ bv,
    float* __restrict__ qT, float* __restrict__ kT, float* __restrict__ vT)
{
    __shared__ float xs[CDIM][64];   // 64 KB exactly; all accesses row-contig

    const int blk = blockIdx.x;           // 0..255
    const int b  = blk >> 6;              // 0..3
    const int n0 = (blk & 63) << 6;       // 0,64,...,4032
    const int t  = threadIdx.x;           // 0..511

    // Stage x tile: x[b, c, n0+nn], coalesced over e.
    const float* xb = x + ((size_t)b * CDIM) * NSEQ + n0;
    for (int e = t; e < CDIM * 64; e += 512) {
        int c = e >> 6, nn = e & 63;
        xs[c][nn] = xb[(size_t)c * NSEQ + nn];
    }
    __syncthreads();

    const int n  = t & 63;
    const int og = __builtin_amdgcn_readfirstlane(t >> 6);  // wave-uniform 0..7

    // ---- V rows: o = og*32 .. og*32+31, in chunks of 8 ----
    float* vrow = vT + ((size_t)(b * NSEQ + n0 + n)) * CDIM;
    for (int ob = 0; ob < 32; ob += 8) {
        const int o0 = og * 32 + ob;
        float acc[8];
        #pragma unroll
        for (int k2 = 0; k2 < 8; ++k2) acc[k2] = bv[o0 + k2];
        #pragma unroll 4
        for (int c = 0; c < CDIM; ++c) {
            float xv = xs[c][n];
            #pragma unroll
            for (int k2 = 0; k2 < 8; ++k2)
                acc[k2] += Wv[(size_t)(o0 + k2) * CDIM + c] * xv;
        }
        *(float4*)&vrow[o0 + 0] = make_float4(acc[0], acc[1], acc[2], acc[3]);
        *(float4*)&vrow[o0 + 4] = make_float4(acc[4], acc[5], acc[6], acc[7]);
    }

    // ---- Q/K rows: combined row r = og*8 .. og*8+7 ----
    const float* Ws = (og < 4) ? Wq : Wk;
    const float* bs = (og < 4) ? bq : bk;
    float* oT       = (og < 4) ? qT : kT;
    const int p0 = (og & 3) * 8;          // row offset within the 32 rows
    {
        float acc[8];
        #pragma unroll
        for (int k2 = 0; k2 < 8; ++k2) acc[k2] = bs[p0 + k2];
        #pragma unroll 4
        for (int c = 0; c < CDIM; ++c) {
            float xv = xs[c][n];
            #pragma unroll
            for (int k2 = 0; k2 < 8; ++k2)
                acc[k2] += Ws[(size_t)(p0 + k2) * CDIM + c] * xv;
        }
        float* orow = oT + ((size_t)(b * NSEQ + n0 + n)) * QPDIM;
        *(float4*)&orow[p0 + 0] = make_float4(acc[0], acc[1], acc[2], acc[3]);
        *(float4*)&orow[p0 + 4] = make_float4(acc[4], acc[5], acc[6], acc[7]);
    }
}

// ---------------------------------------------------------------------------
// Kernel 2: flash attention over softmax axis i.
// grid = B * (N/32) = 512 blocks (XCD-swizzled), 256 threads.
// Thread t <-> channel c = t. Per block: batch b, columns j0..j0+31.
//   kreg[32]  : k_{j0+(t&31)} in registers (reused all K-loop)
//   acc[32]   : out accumulator row c, 32 columns (fp32)
//   per i-tile (32 rows): qs LDS stage -> S tile in LDS -> online softmax
//     stats on first wave -> rescale + PV accumulate (broadcast float4 reads)
// ---------------------------------------------------------------------------
__global__ __launch_bounds__(256) void attn_kernel(
    const float* __restrict__ qT, const float* __restrict__ kT,
    const float* __restrict__ vT, const float* __restrict__ x,
    const float* __restrict__ gamma, float* __restrict__ out)
{
    __shared__ float qs[32][36];   // padded: row stride 144 B (16B-aligned)
    __shared__ float sS[32][36];   // scores then p=exp(s-m); conflict-free
    __shared__ float mj[32], lj[32], alj[32];

    const int blk  = blockIdx.x;
    // XCD swizzle: slot = blk & 7 -> XCD (round-robin heuristic).
    // Batch b pinned to an XCD pair so its ~5 MB q/k/v set stays L2-warm.
    const int slot = blk & 7;
    const int b    = slot >> 1;                       // 0..3
    const int jt   = ((blk >> 3) << 1) | (slot & 1);  // 0..127
    const int j0   = jt << 5;
    const int t    = threadIdx.x;                     // 0..255 == channel c
    const int jlane = t & 31;

    // k_j fragment in registers (32 floats)
    float kreg[32];
    {
        const float* kp = kT + ((size_t)(b * NSEQ + j0 + jlane)) * QPDIM;
        #pragma unroll
        for (int p4 = 0; p4 < 32; p4 += 4) {
            float4 f = *(const float4*)&kp[p4];
            kreg[p4 + 0] = f.x; kreg[p4 + 1] = f.y;
            kreg[p4 + 2] = f.z; kreg[p4 + 3] = f.w;
        }
    }
    if (t < 32) { mj[t] = -1e30f; lj[t] = 0.0f; }

    float acc[32];
    #pragma unroll
    for (int j = 0; j < 32; ++j) acc[j] = 0.0f;
    __syncthreads();

    for (int i0 = 0; i0 < NSEQ; i0 += 32) {
        // Stage q rows for this i-tile (coalesced)
        const float* qb = qT + ((size_t)(b * NSEQ + i0)) * QPDIM;
        for (int e = t; e < 1024; e += 256) {
            int i = e >> 5, p = e & 31;
            qs[i][p] = qb[(size_t)i * QPDIM + p];
        }
        // v column for channel c: coalesced across lanes per i
        float vreg[32];
        {
            const float* vp = vT + ((size_t)(b * NSEQ + i0)) * CDIM + t;
            #pragma unroll
            for (int i = 0; i < 32; ++i) vreg[i] = vp[(size_t)i * CDIM];
        }
        __syncthreads();

        // S[i][j] = q_i . k_j ; thread computes 4 rows for its jlane
        {
            const int ig = (t >> 5) * 4;
            #pragma unroll
            for (int r = 0; r < 4; ++r) {
                const int i = ig + r;
                float d = 0.0f;
                #pragma unroll
                for (int p4 = 0; p4 < 32; p4 += 4) {
                    float4 qv = *(const float4*)&qs[i][p4];
                    d += qv.x * kreg[p4 + 0];
                    d += qv.y * kreg[p4 + 1];
                    d += qv.z * kreg[p4 + 2];
                    d += qv.w * kreg[p4 + 3];
                }
                sS[i][jlane] = d;
            }
        }
        __syncthreads();

        // Online-softmax stats on first wave: 2 half-lanes per column j
        if (t < 64) {
            const int j = t & 31, h = t >> 5;
            float mx = -1e30f;
            #pragma unroll
            for (int i = 0; i < 16; ++i) mx = fmaxf(mx, sS[h * 16 + i][j]);
            const float mold = mj[j];
            const float om   = __shfl_xor(mx, 32);
            const float mnew = fmaxf(fmaxf(mx, om), mold);
            float sum = 0.0f;
            #pragma unroll
            for (int i = 0; i < 16; ++i) {
                float pe = __expf(sS[h * 16 + i][j] - mnew);
                sS[h * 16 + i][j] = pe;
                sum += pe;
            }
            sum += __shfl_xor(sum, 32);
            if (h == 0) {
                float al = __expf(mold - mnew);
                alj[j] = al;
                lj[j]  = lj[j] * al + sum;
                mj[j]  = mnew;
            }
        }
        __syncthreads();

        // Rescale + PV accumulate
        #pragma unroll
        for (int j = 0; j < 32; ++j) acc[j] *= alj[j];  // LDS broadcast
        #pragma unroll
        for (int i = 0; i < 32; ++i) {
            const float vv = vreg[i];
            #pragma unroll
            for (int j4 = 0; j4 < 32; j4 += 4) {
                float4 pp = *(const float4*)&sS[i][j4];  // broadcast b128
                acc[j4 + 0] += pp.x * vv;
                acc[j4 + 1] += pp.y * vv;
                acc[j4 + 2] += pp.z * vv;
                acc[j4 + 3] += pp.w * vv;
            }
        }
        __syncthreads();
    }

    // Epilogue: out = gamma * acc/l + x
    const float g = gamma[0];
    const float* xrow = x   + ((size_t)(b * CDIM + t)) * NSEQ + j0;
    float*       orow = out + ((size_t)(b * CDIM + t)) * NSEQ + j0;
    #pragma unroll
    for (int j4 = 0; j4 < 32; j4 += 4) {
        float4 xv = *(const float4*)&xrow[j4];
        float4 ov;
        ov.x = g * acc[j4 + 0] / lj[j4 + 0] + xv.x;
        ov.y = g * acc[j4 + 1] / lj[j4 + 1] + xv.y;
        ov.z = g * acc[j4 + 2] / lj[j4 + 2] + xv.z;
        ov.w = g * acc[j4 + 3] / lj[j4 + 3] + xv.w;
        *(float4*)&orow[j4] = ov;
    }
}

extern "C" void kernel_launch(void* const* d_in, const int* in_sizes, int n_in,
                              void* d_out, int out_size, void* d_ws, size_t ws_size,
                              hipStream_t stream) {
    const float* x     = (const float*)d_in[0];
    const float* Wq    = (const float*)d_in[1];
    const float* bq    = (const float*)d_in[2];
    const float* Wk    = (const float*)d_in[3];
    const float* bk    = (const float*)d_in[4];
    const float* Wv    = (const float*)d_in[5];
    const float* bv    = (const float*)d_in[6];
    const float* gamma = (const float*)d_in[7];
    float* out = (float*)d_out;

    // Workspace layout (floats): qT[4*4096*32] kT[4*4096*32] vT[4*4096*256]
    float* w  = (float*)d_ws;
    float* qT = w;                       // 524288 floats (2 MB)
    float* kT = w + 524288;              // 524288 floats (2 MB)
    float* vT = w + 1048576;             // 4194304 floats (16 MB)

    qkv_kernel<<<256, 512, 0, stream>>>(x, Wq, bq, Wk, bk, Wv, bv, qT, kT, vT);
    attn_kernel<<<512, 256, 0, stream>>>(qT, kT, vT, x, gamma, out);
}

// Round 2
// 346.168 us; speedup vs baseline: 3.0358x; 3.0358x over previous
//
#include <hip/hip_runtime.h>
#include <hip/hip_bf16.h>
#include <math.h>

// B=4, C=256, N=4096, QP=32.
//   qH[b,n,p] f16, kH[b,j,p] f16   (rows of 32 f16 = 64B)
//   vHT[b,c,n] f16                 (transposed: PV A-frags contiguous)
// attn: per block (b, 32-j tile), flash over i with f16 MFMA:
//   S = q·k^T  (mfma_f32_16x16x32_f16, 1/wave/tile)
//   online softmax (col max via shfl, per-wave running m in regs)
//   P -> f16 -> LDS in B-frag order; PV: 8 mfma/wave/tile, fp32 acc.

#define NBATCH 4
#define CDIM   256
#define NSEQ   4096
#define QPDIM  32

typedef _Float16 half8_t __attribute__((ext_vector_type(8)));
typedef _Float16 half4_t __attribute__((ext_vector_type(4)));
typedef float    floatx4 __attribute__((ext_vector_type(4)));

// ---------------------------------------------------------------------------
// Kernel 1: QKV projections (fp32 VALU compute, f16 outputs).
// grid = 256 blocks, 512 threads. Block: batch b, 64-column tile of n.
// ---------------------------------------------------------------------------
__global__ __launch_bounds__(512) void qkv_kernel(
    const float* __restrict__ x,
    const float* __restrict__ Wq, const float* __restrict__ bq,
    const float* __restrict__ Wk, const float* __restrict__ bk,
    const float* __restrict__ Wv, const float* __restrict__ bv,
    _Float16* __restrict__ qH, _Float16* __restrict__ kH,
    _Float16* __restrict__ vHT)
{
    __shared__ float xs[CDIM][64];

    const int blk = blockIdx.x;
    const int b  = blk >> 6;
    const int n0 = (blk & 63) << 6;
    const int t  = threadIdx.x;

    const float* xb = x + ((size_t)b * CDIM) * NSEQ + n0;
    for (int e = t; e < CDIM * 64; e += 512) {
        int c = e >> 6, nn = e & 63;
        xs[c][nn] = xb[(size_t)c * NSEQ + nn];
    }
    __syncthreads();

    const int n  = t & 63;
    const int og = __builtin_amdgcn_readfirstlane(t >> 6);  // 0..7

    // ---- V: o = og*32 .. og*32+31; store transposed f16 to vHT[b,o,n] ----
    for (int ob = 0; ob < 32; ob += 8) {
        const int o0 = og * 32 + ob;
        float acc[8];
        #pragma unroll
        for (int k2 = 0; k2 < 8; ++k2) acc[k2] = bv[o0 + k2];
        #pragma unroll 4
        for (int c = 0; c < CDIM; ++c) {
            float xv = xs[c][n];
            #pragma unroll
            for (int k2 = 0; k2 < 8; ++k2)
                acc[k2] += Wv[(size_t)(o0 + k2) * CDIM + c] * xv;
        }
        #pragma unroll
        for (int k2 = 0; k2 < 8; ++k2)
            vHT[((size_t)(b * CDIM + o0 + k2)) * NSEQ + n0 + n] =
                (_Float16)acc[k2];
    }

    // ---- Q/K rows (8 per wave-group), f16 packed store ----
    const float* Ws = (og < 4) ? Wq : Wk;
    const float* bs = (og < 4) ? bq : bk;
    _Float16* oT    = (og < 4) ? qH : kH;
    const int p0 = (og & 3) * 8;
    {
        float acc[8];
        #pragma unroll
        for (int k2 = 0; k2 < 8; ++k2) acc[k2] = bs[p0 + k2];
        #pragma unroll 4
        for (int c = 0; c < CDIM; ++c) {
            float xv = xs[c][n];
            #pragma unroll
            for (int k2 = 0; k2 < 8; ++k2)
                acc[k2] += Ws[(size_t)(p0 + k2) * CDIM + c] * xv;
        }
        half8_t h;
        #pragma unroll
        for (int k2 = 0; k2 < 8; ++k2) h[k2] = (_Float16)acc[k2];
        *(half8_t*)(oT + ((size_t)(b * NSEQ + n0 + n)) * QPDIM + p0) = h;
    }
}

// ---------------------------------------------------------------------------
// Kernel 2: flash attention, f16 MFMA. grid = 512 (XCD-swizzled), 256 thr.
// Wave w: mi = w&1 (S row-halves), nj = w>>1 (j 16-col halves).
// PV: wave w owns output rows c in [w*64, w*64+64).
// ---------------------------------------------------------------------------
__global__ __launch_bounds__(256) void attn_kernel(
    const _Float16* __restrict__ qH, const _Float16* __restrict__ kH,
    const _Float16* __restrict__ vHT, const float* __restrict__ x,
    const float* __restrict__ gamma, float* __restrict__ out)
{
    __shared__ _Float16 pT[2][32][40];   // [buf][j][i], row 80B (16B-aligned)
    __shared__ float wmax[2][32];        // [mi][j]
    __shared__ float acol[32];           // alpha per j
    __shared__ float lred[2][32];        // [mi][j]
    __shared__ float rv[32];             // gamma / l per j

    const int blk  = blockIdx.x;
    const int slot = blk & 7;                          // XCD round-robin
    const int b    = slot >> 1;                        // batch -> XCD pair
    const int jt   = ((blk >> 3) << 1) | (slot & 1);   // 0..127
    const int j0   = jt << 5;
    const int t    = threadIdx.x;
    const int w    = t >> 6;
    const int lane = t & 63;
    const int quad = lane >> 4;
    const int col  = lane & 15;
    const int mi   = w & 1, nj = w >> 1;

    // K B-fragment (persistent across the whole i-loop):
    // B[k=p][n=j]: lane holds row (j0+nj*16+col) of kH, p = quad*8..+7.
    const half8_t kb = *(const half8_t*)(
        kH + ((size_t)(b * NSEQ + j0 + nj * 16 + col)) * QPDIM + quad * 8);

    floatx4 acc[4][2];
    #pragma unroll
    for (int mt = 0; mt < 4; ++mt)
        #pragma unroll
        for (int n2 = 0; n2 < 2; ++n2)
            acc[mt][n2] = (floatx4){0.f, 0.f, 0.f, 0.f};

    float m_run = -1e30f;
    float lpart = 0.0f;

    const _Float16* qbase =
        qH + ((size_t)(b * NSEQ + mi * 16 + col)) * QPDIM + quad * 8;
    const _Float16* vbase =
        vHT + ((size_t)(b * CDIM + w * 64 + col)) * NSEQ + quad * 8;

    int pb = 0;
    for (int i0 = 0; i0 < NSEQ; i0 += 32) {
        // ---- S tile: A[m=i][k=p] from qH, one MFMA per wave ----
        half8_t qa = *(const half8_t*)(qbase + (size_t)i0 * QPDIM);
        floatx4 S = __builtin_amdgcn_mfma_f32_16x16x32_f16(
            qa, kb, (floatx4){0.f, 0.f, 0.f, 0.f}, 0, 0, 0);

        // column max over this wave's 16 rows (4 regs + cross-quad shfl)
        float mx = fmaxf(fmaxf(S[0], S[1]), fmaxf(S[2], S[3]));
        mx = fmaxf(mx, __shfl_xor(mx, 16));
        mx = fmaxf(mx, __shfl_xor(mx, 32));
        if (lane < 16) wmax[mi][nj * 16 + col] = mx;
        __syncthreads();  // b1: wmax ready

        // running max + alpha (deterministic duplicate across the mi pair)
        float tm    = fmaxf(wmax[0][nj * 16 + col], wmax[1][nj * 16 + col]);
        float m_new = fmaxf(m_run, tm);
        float al    = __expf(m_run - m_new);
        m_run = m_new;

        float p0 = __expf(S[0] - m_new), p1 = __expf(S[1] - m_new);
        float p2 = __expf(S[2] - m_new), p3 = __expf(S[3] - m_new);
        half4_t ph = {(_Float16)p0, (_Float16)p1, (_Float16)p2, (_Float16)p3};
        // pT[j][i]: rows ordered so PV B-frag is one ds_read_b128
        *(half4_t*)&pT[pb][nj * 16 + col][mi * 16 + quad * 4] = ph;
        if (lane < 16) acol[nj * 16 + col] = al;
        lpart = lpart * al + (p0 + p1 + p2 + p3);

        // v A-frags for this tile (L2-hot 16B loads; barrier drains them)
        half8_t va[4];
        #pragma unroll
        for (int mt = 0; mt < 4; ++mt)
            va[mt] = *(const half8_t*)(vbase + (size_t)mt * 16 * NSEQ + i0);
        __syncthreads();  // b2: pT + acol ready

        // rescale + PV MFMAs
        float a0 = acol[col], a1 = acol[16 + col];
        #pragma unroll
        for (int mt = 0; mt < 4; ++mt) { acc[mt][0] *= a0; acc[mt][1] *= a1; }
        half8_t pB0 = *(const half8_t*)&pT[pb][col][quad * 8];
        half8_t pB1 = *(const half8_t*)&pT[pb][16 + col][quad * 8];
        #pragma unroll
        for (int mt = 0; mt < 4; ++mt) {
            acc[mt][0] = __builtin_amdgcn_mfma_f32_16x16x32_f16(
                va[mt], pB0, acc[mt][0], 0, 0, 0);
            acc[mt][1] = __builtin_amdgcn_mfma_f32_16x16x32_f16(
                va[mt], pB1, acc[mt][1], 0, 0, 0);
        }
        pb ^= 1;
    }

    // ---- l reduction and epilogue ----
    lpart += __shfl_xor(lpart, 16);
    lpart += __shfl_xor(lpart, 32);
    if (lane < 16) lred[mi][nj * 16 + col] = lpart;
    __syncthreads();
    if (t < 32) rv[t] = gamma[0] / (lred[0][t] + lred[1][t]);
    __syncthreads();

    float rv0 = rv[col], rv1 = rv[16 + col];
    #pragma unroll
    for (int mt = 0; mt < 4; ++mt) {
        #pragma unroll
        for (int reg = 0; reg < 4; ++reg) {
            int c = w * 64 + mt * 16 + quad * 4 + reg;
            size_t off = ((size_t)(b * CDIM + c)) * NSEQ + j0 + col;
            out[off]      = acc[mt][0][reg] * rv0 + x[off];
            out[off + 16] = acc[mt][1][reg] * rv1 + x[off + 16];
        }
    }
}

extern "C" void kernel_launch(void* const* d_in, const int* in_sizes, int n_in,
                              void* d_out, int out_size, void* d_ws, size_t ws_size,
                              hipStream_t stream) {
    const float* x     = (const float*)d_in[0];
    const float* Wq    = (const float*)d_in[1];
    const float* bq    = (const float*)d_in[2];
    const float* Wk    = (const float*)d_in[3];
    const float* bk    = (const float*)d_in[4];
    const float* Wv    = (const float*)d_in[5];
    const float* bv    = (const float*)d_in[6];
    const float* gamma = (const float*)d_in[7];
    float* out = (float*)d_out;

    // ws layout (f16): qH 4*4096*32, kH 4*4096*32, vHT 4*256*4096  (10.5 MB)
    _Float16* w16 = (_Float16*)d_ws;
    _Float16* qH  = w16;
    _Float16* kH  = w16 + (size_t)NBATCH * NSEQ * QPDIM;
    _Float16* vHT = w16 + (size_t)2 * NBATCH * NSEQ * QPDIM;

    qkv_kernel<<<256, 512, 0, stream>>>(x, Wq, bq, Wk, bk, Wv, bv, qH, kH, vHT);
    attn_kernel<<<512, 256, 0, stream>>>(qH, kH, vHT, x, gamma, out);
}

// Round 3
// 208.383 us; speedup vs baseline: 5.0432x; 1.6612x over previous
//
#include <hip/hip_runtime.h>
#include <hip/hip_bf16.h>
#include <math.h>

// B=4, C=256, N=4096, QP=32.
// ws: qH[b][n][32] f16, kH[b][n][32] f16, vHT[b][c][n] f16.
// qkv: MFMA GEMM, rows = concat[Wv(256); Wq(32); Wk(32)] = 320.
// attn: two-pass per block (b, 32 j): pass A = m_j (max only);
//       pass B = flash PV with fixed m (no rescale), l as by-product.

#define NBATCH 4
#define CDIM   256
#define NSEQ   4096
#define QPDIM  32

typedef _Float16 half8_t __attribute__((ext_vector_type(8)));
typedef _Float16 half4_t __attribute__((ext_vector_type(4)));
typedef float    floatx4 __attribute__((ext_vector_type(4)));

// ---------------------------------------------------------------------------
// Kernel 1: QKV as MFMA GEMM. grid = 5 row-groups * 4 b * 64 n-tiles = 1280
// blocks, 256 thr (4 waves). Wave w: m-tile (mg*4+w) = 16 rows, 64 n cols.
// W A-frags persistent in regs (fp32->f16 cvt once); x-tile transposed in LDS.
// ---------------------------------------------------------------------------
__global__ __launch_bounds__(256, 4) void qkv_kernel(
    const float* __restrict__ x,
    const float* __restrict__ Wq, const float* __restrict__ bq,
    const float* __restrict__ Wk, const float* __restrict__ bk,
    const float* __restrict__ Wv, const float* __restrict__ bv,
    _Float16* __restrict__ qH, _Float16* __restrict__ kH,
    _Float16* __restrict__ vHT)
{
    __shared__ _Float16 xT[64][264];   // [n][c], +8 pad: 2-way banks max

    const int blk  = blockIdx.x;
    const int mg   = blk % 5;            // row-group: rows mg*64 .. +63
    const int rest = blk / 5;
    const int b    = rest & 3;
    const int n0   = (rest >> 2) << 6;   // 64-col tile

    const int t    = threadIdx.x;
    const int w    = t >> 6;
    const int lane = t & 63;
    const int quad = lane >> 4;
    const int col  = lane & 15;

    // ---- stage x tile transposed (fp32 -> f16) ----
    {
        const int nq = t & 3;            // n quarter (16 n)
        const int cb = t >> 2;           // 0..63
        for (int pass = 0; pass < 4; ++pass) {
            const int c = pass * 64 + cb;
            const float* xp = x + ((size_t)(b * CDIM + c)) * NSEQ + n0 + nq * 16;
            float4 f[4];
            #pragma unroll
            for (int g = 0; g < 4; ++g) f[g] = ((const float4*)xp)[g];
            #pragma unroll
            for (int g = 0; g < 4; ++g) {
                xT[nq * 16 + g * 4 + 0][c] = (_Float16)f[g].x;
                xT[nq * 16 + g * 4 + 1][c] = (_Float16)f[g].y;
                xT[nq * 16 + g * 4 + 2][c] = (_Float16)f[g].z;
                xT[nq * 16 + g * 4 + 3][c] = (_Float16)f[g].w;
            }
        }
    }

    // ---- W A-frags (persistent): rows r0..r0+15, all 256 k ----
    const int m  = mg * 4 + w;
    const int r0 = m * 16;
    const float* Wrow; const float* brow;
    int rloc;
    if (r0 < 256)      { Wrow = Wv; brow = bv; rloc = r0; }
    else if (r0 < 288) { Wrow = Wq; brow = bq; rloc = r0 - 256; }
    else               { Wrow = Wk; brow = bk; rloc = r0 - 288; }

    half8_t a[8];
    {
        const float* wp = Wrow + (size_t)(rloc + col) * CDIM + quad * 8;
        #pragma unroll
        for (int kq = 0; kq < 8; ++kq) {
            float4 f0 = *(const float4*)(wp + kq * 32);
            float4 f1 = *(const float4*)(wp + kq * 32 + 4);
            half8_t h;
            h[0] = (_Float16)f0.x; h[1] = (_Float16)f0.y;
            h[2] = (_Float16)f0.z; h[3] = (_Float16)f0.w;
            h[4] = (_Float16)f1.x; h[5] = (_Float16)f1.y;
            h[6] = (_Float16)f1.z; h[7] = (_Float16)f1.w;
            a[kq] = h;
        }
    }
    __syncthreads();

    // ---- GEMM: 8 k-steps x 4 n-tiles ----
    floatx4 acc[4];
    #pragma unroll
    for (int j = 0; j < 4; ++j) acc[j] = (floatx4){0.f, 0.f, 0.f, 0.f};
    #pragma unroll
    for (int kq = 0; kq < 8; ++kq) {
        #pragma unroll
        for (int j = 0; j < 4; ++j) {
            half8_t bf = *(const half8_t*)&xT[j * 16 + col][kq * 32 + quad * 8];
            acc[j] = __builtin_amdgcn_mfma_f32_16x16x32_f16(a[kq], bf, acc[j], 0, 0, 0);
        }
    }

    // ---- epilogue: bias + store to layout per row type ----
    float bias[4];
    #pragma unroll
    for (int reg = 0; reg < 4; ++reg) bias[reg] = brow[rloc + quad * 4 + reg];

    #pragma unroll
    for (int j = 0; j < 4; ++j) {
        const int n = n0 + j * 16 + col;
        #pragma unroll
        for (int reg = 0; reg < 4; ++reg) {
            const int rl = rloc + quad * 4 + reg;
            const float val = acc[j][reg] + bias[reg];
            if (r0 < 256)
                vHT[((size_t)(b * CDIM + rl)) * NSEQ + n] = (_Float16)val;
            else if (r0 < 288)
                qH[((size_t)(b * NSEQ + n)) * QPDIM + rl] = (_Float16)val;
            else
                kH[((size_t)(b * NSEQ + n)) * QPDIM + rl] = (_Float16)val;
        }
    }
}

// ---------------------------------------------------------------------------
// Kernel 2: two-pass flash attention. grid = 512 (XCD-swizzled), 256 thr.
// Pass A: m_j = max_i s_ij (waves split i 4-ways; no exp).
// Pass B: per 64-i tile: phase1 (waves=i-quarters): S + exp(s-m) + P->LDS;
//         phase2 (waves=c-quarters): 16 PV MFMAs from swizzled v LDS tile.
// v staged by global_load_lds (XOR-swizzled source so reads are 2-way max).
// ---------------------------------------------------------------------------
__global__ __launch_bounds__(256, 2) void attn_kernel(
    const _Float16* __restrict__ qH, const _Float16* __restrict__ kH,
    const _Float16* __restrict__ vHT, const float* __restrict__ x,
    const float* __restrict__ gamma, float* __restrict__ out)
{
    __shared__ _Float16 vbuf[2][16384];  // 2 x 32KB: [c 256][8 units ^ (c&7)]
    __shared__ _Float16 qs[64][40];      // [i][p], +8 pad
    __shared__ _Float16 Ps[32][72];      // [j][i], +8 pad
    __shared__ float mred[4][32], lred[4][32], ms[32], rv[32];

    const int blk  = blockIdx.x;
    const int slot = blk & 7;                          // XCD round-robin
    const int b    = slot >> 1;
    const int jblk = ((blk >> 3) << 1) | (slot & 1);   // 0..127
    const int j0   = jblk << 5;
    const int t    = threadIdx.x;
    const int w    = t >> 6;
    const int lane = t & 63;
    const int quad = lane >> 4;
    const int col  = lane & 15;

    const _Float16* qg = qH + (size_t)b * NSEQ * QPDIM;
    const _Float16* vg = vHT + (size_t)b * CDIM * NSEQ;

    // persistent K B-frags for the two j-16 tiles
    const half8_t kb0 = *(const half8_t*)(
        kH + ((size_t)(b * NSEQ + j0 + col)) * QPDIM + quad * 8);
    const half8_t kb1 = *(const half8_t*)(
        kH + ((size_t)(b * NSEQ + j0 + 16 + col)) * QPDIM + quad * 8);

    // ================= pass A: column max =================
    float mx0 = -1e30f, mx1 = -1e30f;
    for (int it = 0; it < 16; ++it) {
        const int ibase = w * 1024 + it * 64;
        #pragma unroll
        for (int iq = 0; iq < 4; ++iq) {
            half8_t qa = *(const half8_t*)(
                qg + (size_t)(ibase + iq * 16 + col) * QPDIM + quad * 8);
            floatx4 S0 = __builtin_amdgcn_mfma_f32_16x16x32_f16(
                qa, kb0, (floatx4){0.f, 0.f, 0.f, 0.f}, 0, 0, 0);
            floatx4 S1 = __builtin_amdgcn_mfma_f32_16x16x32_f16(
                qa, kb1, (floatx4){0.f, 0.f, 0.f, 0.f}, 0, 0, 0);
            mx0 = fmaxf(mx0, fmaxf(fmaxf(S0[0], S0[1]), fmaxf(S0[2], S0[3])));
            mx1 = fmaxf(mx1, fmaxf(fmaxf(S1[0], S1[1]), fmaxf(S1[2], S1[3])));
        }
    }
    mx0 = fmaxf(mx0, __shfl_xor(mx0, 16)); mx0 = fmaxf(mx0, __shfl_xor(mx0, 32));
    mx1 = fmaxf(mx1, __shfl_xor(mx1, 16)); mx1 = fmaxf(mx1, __shfl_xor(mx1, 32));
    if (lane < 16) { mred[w][col] = mx0; mred[w][16 + col] = mx1; }
    __syncthreads();
    if (t < 32)
        ms[t] = fmaxf(fmaxf(mred[0][t], mred[1][t]),
                      fmaxf(mred[2][t], mred[3][t]));
    __syncthreads();
    const float mfix0 = ms[col], mfix1 = ms[16 + col];

    // ================= pass B =================
    floatx4 acc[4][2];
    #pragma unroll
    for (int mt = 0; mt < 4; ++mt) {
        acc[mt][0] = (floatx4){0.f, 0.f, 0.f, 0.f};
        acc[mt][1] = (floatx4){0.f, 0.f, 0.f, 0.f};
    }
    float lp0 = 0.f, lp1 = 0.f;

    const int qi   = t >> 2;     // staging: i row
    const int qpt  = t & 3;      // staging: 16B part

    // DMA wave w's units [w*512, w*512+512) of v tile; XOR-swizzled source
    #define DMA_V(i0_, buf_)                                                   \
        {                                                                      \
            _Pragma("unroll")                                                  \
            for (int nn = 0; nn < 8; ++nn) {                                   \
                const int u   = w * 512 + nn * 64 + lane;                      \
                const int c_  = u >> 3;                                        \
                const int ihx = (u & 7) ^ (c_ & 7);                            \
                const _Float16* src = vg + (size_t)c_ * NSEQ + (i0_) + ihx * 8;\
                __builtin_amdgcn_global_load_lds(                              \
                    (const __attribute__((address_space(1))) void*)src,        \
                    (__attribute__((address_space(3))) void*)                  \
                        (&vbuf[buf_][(w * 512 + nn * 64) * 8]),                \
                    16, 0, 0);                                                 \
            }                                                                  \
        }

    DMA_V(0, 0);
    {   // stage q tile 0
        half8_t q0 = *(const half8_t*)(qg + (size_t)qi * QPDIM + qpt * 8);
        *(half8_t*)&qs[qi][qpt * 8] = q0;
    }

    int cur = 0;
    for (int i0 = 0; i0 < NSEQ; i0 += 64) {
        const bool more = (i0 + 64 < NSEQ);
        half8_t qnext;
        if (more)
            qnext = *(const half8_t*)(
                qg + (size_t)(i0 + 64 + qi) * QPDIM + qpt * 8);

        __syncthreads();  // B1: v[cur] DMA done, qs(t) written, Ps(t-1) free

        // ---- phase 1: wave w = i-quarter ----
        half8_t qa = *(const half8_t*)&qs[w * 16 + col][quad * 8];
        floatx4 S0 = __builtin_amdgcn_mfma_f32_16x16x32_f16(
            qa, kb0, (floatx4){0.f, 0.f, 0.f, 0.f}, 0, 0, 0);
        floatx4 S1 = __builtin_amdgcn_mfma_f32_16x16x32_f16(
            qa, kb1, (floatx4){0.f, 0.f, 0.f, 0.f}, 0, 0, 0);
        half4_t p0h, p1h;
        #pragma unroll
        for (int r = 0; r < 4; ++r) {
            float p0 = __expf(S0[r] - mfix0); lp0 += p0; p0h[r] = (_Float16)p0;
            float p1 = __expf(S1[r] - mfix1); lp1 += p1; p1h[r] = (_Float16)p1;
        }
        *(half4_t*)&Ps[col][w * 16 + quad * 4]      = p0h;
        *(half4_t*)&Ps[16 + col][w * 16 + quad * 4] = p1h;

        __syncthreads();  // B2: Ps ready, qs(t) consumed

        if (more) {
            *(half8_t*)&qs[qi][qpt * 8] = qnext;
            DMA_V(i0 + 64, cur ^ 1);
        }

        // ---- phase 2: wave w = c-quarter [w*64, +64) ----
        half8_t pB00 = *(const half8_t*)&Ps[col][quad * 8];
        half8_t pB01 = *(const half8_t*)&Ps[col][32 + quad * 8];
        half8_t pB10 = *(const half8_t*)&Ps[16 + col][quad * 8];
        half8_t pB11 = *(const half8_t*)&Ps[16 + col][32 + quad * 8];
        #pragma unroll
        for (int mt = 0; mt < 4; ++mt) {
            const int c_ = w * 64 + mt * 16 + col;
            const int u0 = c_ * 8 + ((0 * 4 + quad) ^ (c_ & 7));
            const int u1 = c_ * 8 + ((1 * 4 + quad) ^ (c_ & 7));
            half8_t va0 = *(const half8_t*)&vbuf[cur][u0 * 8];
            half8_t va1 = *(const half8_t*)&vbuf[cur][u1 * 8];
            acc[mt][0] = __builtin_amdgcn_mfma_f32_16x16x32_f16(
                va0, pB00, acc[mt][0], 0, 0, 0);
            acc[mt][1] = __builtin_amdgcn_mfma_f32_16x16x32_f16(
                va0, pB10, acc[mt][1], 0, 0, 0);
            acc[mt][0] = __builtin_amdgcn_mfma_f32_16x16x32_f16(
                va1, pB01, acc[mt][0], 0, 0, 0);
            acc[mt][1] = __builtin_amdgcn_mfma_f32_16x16x32_f16(
                va1, pB11, acc[mt][1], 0, 0, 0);
        }
        cur ^= 1;
    }

    // ---- l reduction + epilogue ----
    lp0 += __shfl_xor(lp0, 16); lp0 += __shfl_xor(lp0, 32);
    lp1 += __shfl_xor(lp1, 16); lp1 += __shfl_xor(lp1, 32);
    if (lane < 16) { lred[w][col] = lp0; lred[w][16 + col] = lp1; }
    __syncthreads();
    if (t < 32) {
        float l = lred[0][t] + lred[1][t] + lred[2][t] + lred[3][t];
        rv[t] = gamma[0] / l;
    }
    __syncthreads();

    const float rv0 = rv[col], rv1 = rv[16 + col];
    #pragma unroll
    for (int mt = 0; mt < 4; ++mt) {
        #pragma unroll
        for (int reg = 0; reg < 4; ++reg) {
            const int c_ = w * 64 + mt * 16 + quad * 4 + reg;
            const size_t off = ((size_t)(b * CDIM + c_)) * NSEQ + j0 + col;
            out[off]      = acc[mt][0][reg] * rv0 + x[off];
            out[off + 16] = acc[mt][1][reg] * rv1 + x[off + 16];
        }
    }
}

extern "C" void kernel_launch(void* const* d_in, const int* in_sizes, int n_in,
                              void* d_out, int out_size, void* d_ws, size_t ws_size,
                              hipStream_t stream) {
    const float* x     = (const float*)d_in[0];
    const float* Wq    = (const float*)d_in[1];
    const float* bq    = (const float*)d_in[2];
    const float* Wk    = (const float*)d_in[3];
    const float* bk    = (const float*)d_in[4];
    const float* Wv    = (const float*)d_in[5];
    const float* bv    = (const float*)d_in[6];
    const float* gamma = (const float*)d_in[7];
    float* out = (float*)d_out;

    _Float16* w16 = (_Float16*)d_ws;
    _Float16* qH  = w16;                                     // 1 MB
    _Float16* kH  = w16 + (size_t)NBATCH * NSEQ * QPDIM;     // 1 MB
    _Float16* vHT = w16 + (size_t)2 * NBATCH * NSEQ * QPDIM; // 8 MB

    qkv_kernel<<<1280, 256, 0, stream>>>(x, Wq, bq, Wk, bk, Wv, bv, qH, kH, vHT);
    attn_kernel<<<512, 256, 0, stream>>>(qH, kH, vHT, x, gamma, out);
}